// Round 2
// baseline (477.533 us; speedup 1.0000x reference)
//
#include <hip/hip_runtime.h>

#define MU_C     0.5f
#define C_NORM_C 8.0f
#define CG_IT    10
#define LRELU_C  0.2f
#define EPS_C    1e-12f

constexpr int BB = 16;   // batch
constexpr int KK = 16;   // neighbors
constexpr int EE = 6;    // embedding dim

// ws scalar slots (floats):
// sc[0]           : norm accumulator (sum deg^2 + sum w^2)
// sc[1]           : musc = MU * C / sqrt(sc[0])
// sc[32+16i + b]  : gamma_i[b] = r_i . r_i   (i = 0..10)
// sc[224+16i + b] : delta_i[b] = r_i . A r_i (i = 0..9)
#define GAM 32
#define DEL 224

__global__ void k_zero_scalars(float* sc) {
    sc[threadIdx.x] = 0.0f;
}

// f = LeakyReLU(W [x, emb] + b), stored padded (N, 16, 4) for aligned float4 gathers
__global__ void k_feat(const float* __restrict__ x,
                       const float* __restrict__ emb,
                       const float* __restrict__ fcw,
                       const float* __restrict__ fcb,
                       float* __restrict__ ffp,
                       int N) {
    int n = blockIdx.x * blockDim.x + threadIdx.x;
    if (n >= N) return;
    float ev[EE];
#pragma unroll
    for (int j = 0; j < EE; ++j) ev[j] = emb[(size_t)n * EE + j];
    float g[3], w0[3];
#pragma unroll
    for (int f = 0; f < 3; ++f) {
        w0[f] = fcw[f * (EE + 1)];
        float s = fcb[f];
#pragma unroll
        for (int j = 0; j < EE; ++j) s += fcw[f * (EE + 1) + 1 + j] * ev[j];
        g[f] = s;
    }
    float o[BB * 4];
#pragma unroll
    for (int b = 0; b < BB; ++b) {
        float xv = x[(size_t)b * N + n];
#pragma unroll
        for (int f = 0; f < 3; ++f) {
            float v = g[f] + w0[f] * xv;
            o[b * 4 + f] = (v >= 0.f) ? v : LRELU_C * v;
        }
        o[b * 4 + 3] = 0.f;
    }
    float4* dst = (float4*)(ffp + (size_t)n * 64);
#pragma unroll
    for (int q = 0; q < 16; ++q) dst[q] = ((const float4*)o)[q];
}

// batch-parallel similarity weights: thread = (node n, batch b); 16 lanes of a
// node cooperatively gather each neighbor's 256B feature row (coalesced).
__global__ void k_weights(const int* __restrict__ nl,
                          const float* __restrict__ ffp,
                          const float* __restrict__ theta_p,
                          float* __restrict__ wl,
                          float* __restrict__ sc,
                          int N) {
    __shared__ float lds[4];
    int t = blockIdx.x * blockDim.x + threadIdx.x;
    int n = t >> 4, b = t & 15;
    float tp = 0.f;
    if (n < N) {
        float inv2t = 0.5f / theta_p[0];
        float4 fs = *(const float4*)(ffp + (size_t)n * 64 + b * 4);
        int kidx = nl[(size_t)n * KK + b];      // lane b holds neighbor index k=b
        int ksafe = kidx < 0 ? 0 : kidx;
        float myw = 0.f;
#pragma unroll
        for (int k = 0; k < KK; ++k) {
            int nbr = __shfl(ksafe, k, 16);     // broadcast k-th neighbor in group
            float4 fn = *(const float4*)(ffp + (size_t)nbr * 64 + b * 4);
            float d0 = fs.x - fn.x, d1 = fs.y - fn.y, d2 = fs.z - fn.z;
            float e = __expf(-(d0 * d0 + d1 * d1 + d2 * d2) * inv2t);
            e += __shfl_xor(e, 1, 16);
            e += __shfl_xor(e, 2, 16);
            e += __shfl_xor(e, 4, 16);
            e += __shfl_xor(e, 8, 16);
            if (k == b) myw = e * (1.f / BB);
        }
        if (kidx < 0) myw = 0.f;
        wl[(size_t)n * KK + b] = myw;
        float deg = myw, sw2 = myw * myw;
#pragma unroll
        for (int off = 1; off < 16; off <<= 1) {
            deg += __shfl_xor(deg, off, 16);
            sw2 += __shfl_xor(sw2, off, 16);
        }
        if (b == 0) tp = deg * deg + sw2;
    }
    // group leaders sit at lanes 0,16,32,48 of each wave
    tp += __shfl_xor(tp, 16, 64);
    tp += __shfl_xor(tp, 32, 64);
    int lane = threadIdx.x & 63, wid = threadIdx.x >> 6;
    if (lane == 0) lds[wid] = tp;
    __syncthreads();
    if (threadIdx.x == 0) {
        float ssum = 0.f;
        int nw = blockDim.x >> 6;
        for (int wv = 0; wv < nw; ++wv) ssum += lds[wv];
        atomicAdd(sc, ssum);
    }
}

__global__ void k_scale(float* sc) {
    if (threadIdx.x == 0) sc[1] = MU_C * C_NORM_C / sqrtf(sc[0]);
}

// stride-4 lane-partitioned 16-slot block reduction + one atomic per block
__device__ __forceinline__ void reduce_q4_atomic(float part[4], float* lds, float* target) {
#pragma unroll
    for (int j = 0; j < 4; ++j) {
#pragma unroll
        for (int off = 32; off >= 4; off >>= 1) part[j] += __shfl_down(part[j], off);
    }
    int lane = threadIdx.x & 63, wid = threadIdx.x >> 6;
    if (lane < 4) {
#pragma unroll
        for (int j = 0; j < 4; ++j) lds[wid * 16 + lane * 4 + j] = part[j];
    }
    __syncthreads();
    if (threadIdx.x < 16) {
        float s = 0.f;
        int nw = blockDim.x >> 6;
        for (int wv = 0; wv < nw; ++wv) s += lds[wv * 16 + threadIdx.x];
        atomicAdd(target + threadIdx.x, s);
    }
}

// r = x^T (N,16 layout), gamma_0 = r.r
__global__ void k_init(const float* __restrict__ x,
                       float* __restrict__ r,
                       float* __restrict__ sc,
                       int N) {
    __shared__ float lds[64];
    int t = blockIdx.x * blockDim.x + threadIdx.x;
    float part[4] = {0.f, 0.f, 0.f, 0.f};
    if (t < N * 4) {
        int n = t >> 2, q = t & 3;
        float v0 = x[(size_t)(q * 4 + 0) * N + n];
        float v1 = x[(size_t)(q * 4 + 1) * N + n];
        float v2 = x[(size_t)(q * 4 + 2) * N + n];
        float v3 = x[(size_t)(q * 4 + 3) * N + n];
        part[0] = v0 * v0; part[1] = v1 * v1; part[2] = v2 * v2; part[3] = v3 * v3;
        *(float4*)(r + (size_t)n * 16 + q * 4) = make_float4(v0, v1, v2, v3);
    }
    reduce_q4_atomic(part, lds, sc + GAM);
}

// Chronopoulos-Gear apply: ar = (I + musc*L) r ; delta_i = r.ar ;
// p = r + beta_i p ; s = ar + beta_i s   (beta_i from gamma slots, 0 at iter 0)
__global__ void k_apply(const float* __restrict__ wl,
                        const int* __restrict__ nl,
                        const float* __restrict__ r,
                        float* __restrict__ p,
                        float* __restrict__ s,
                        float* __restrict__ sc,
                        int iter, int N) {
    __shared__ float lds[64];
    int t = blockIdx.x * blockDim.x + threadIdx.x;
    float part[4] = {0.f, 0.f, 0.f, 0.f};
    if (t < N * 4) {
        int n = t >> 2, q = t & 3;
        float musc = sc[1];
        size_t o = (size_t)n * 16 + q * 4;
        float4 rq = *(const float4*)(r + o);
        int idx[KK];
#pragma unroll
        for (int qq = 0; qq < 4; ++qq)
            ((int4*)idx)[qq] = ((const int4*)(nl + (size_t)n * KK))[qq];
        float wr[KK];
#pragma unroll
        for (int qq = 0; qq < 4; ++qq)
            ((float4*)wr)[qq] = ((const float4*)(wl + (size_t)n * KK))[qq];
        float a0 = 0.f, a1 = 0.f, a2 = 0.f, a3 = 0.f;
#pragma unroll
        for (int k = 0; k < KK; ++k) {
            int nb = idx[k] < 0 ? 0 : idx[k];
            float4 rn = *(const float4*)(r + (size_t)nb * 16 + q * 4);
            float wk = wr[k];
            a0 += wk * (rq.x - rn.x);
            a1 += wk * (rq.y - rn.y);
            a2 += wk * (rq.z - rn.z);
            a3 += wk * (rq.w - rn.w);
        }
        float4 ar;
        ar.x = rq.x + musc * a0;
        ar.y = rq.y + musc * a1;
        ar.z = rq.z + musc * a2;
        ar.w = rq.w + musc * a3;
        part[0] = rq.x * ar.x; part[1] = rq.y * ar.y;
        part[2] = rq.z * ar.z; part[3] = rq.w * ar.w;
        float4 pn, sn;
        if (iter == 0) {
            pn = rq; sn = ar;
        } else {
            const float* g  = sc + GAM + 16 * iter;
            const float* gp = g - 16;
            float b0 = g[q * 4 + 0] / (gp[q * 4 + 0] + EPS_C);
            float b1 = g[q * 4 + 1] / (gp[q * 4 + 1] + EPS_C);
            float b2 = g[q * 4 + 2] / (gp[q * 4 + 2] + EPS_C);
            float b3 = g[q * 4 + 3] / (gp[q * 4 + 3] + EPS_C);
            float4 po = *(const float4*)(p + o);
            float4 so = *(const float4*)(s + o);
            pn.x = rq.x + b0 * po.x; pn.y = rq.y + b1 * po.y;
            pn.z = rq.z + b2 * po.z; pn.w = rq.w + b3 * po.w;
            sn.x = ar.x + b0 * so.x; sn.y = ar.y + b1 * so.y;
            sn.z = ar.z + b2 * so.z; sn.w = ar.w + b3 * so.w;
        }
        *(float4*)(p + o) = pn;
        *(float4*)(s + o) = sn;
    }
    reduce_q4_atomic(part, lds, sc + DEL + 16 * iter);
}

// x += alpha_i p ; r -= alpha_i s ; gamma_{i+1} = r.r
// alpha chain reconstructed from gamma/delta slots:
//   beta_j = g_j/(g_{j-1}+eps); alpha_j = g_j/(d_j - beta_j g_j/alpha_{j-1} + eps)
// Last iteration writes out = x + alpha p in (B,N) layout directly.
__global__ void k_upd(float* __restrict__ sc,
                      float* __restrict__ x,
                      const float* __restrict__ p,
                      const float* __restrict__ s,
                      float* __restrict__ r,
                      float* __restrict__ out,
                      int iter, int N) {
    __shared__ float lds[64];
    int t = blockIdx.x * blockDim.x + threadIdx.x;
    float part[4] = {0.f, 0.f, 0.f, 0.f};
    if (t < N * 4) {
        int n = t >> 2, q = t & 3;
        float al[4];
#pragma unroll
        for (int j = 0; j < 4; ++j) {
            int b = q * 4 + j;
            float alpha = 0.f;
            for (int it = 0; it <= iter; ++it) {
                float g = sc[GAM + 16 * it + b];
                float d = sc[DEL + 16 * it + b];
                float denom;
                if (it == 0) {
                    denom = d;
                } else {
                    float gp = sc[GAM + 16 * (it - 1) + b];
                    float beta = g / (gp + EPS_C);
                    denom = d - beta * g / alpha;
                }
                alpha = g / (denom + EPS_C);
            }
            al[j] = alpha;
        }
        size_t o = (size_t)n * 16 + q * 4;
        float4 pq = *(const float4*)(p + o);
        float4 xq;
        if (iter == 0) {
            xq.x = al[0] * pq.x; xq.y = al[1] * pq.y;
            xq.z = al[2] * pq.z; xq.w = al[3] * pq.w;
        } else {
            xq = *(const float4*)(x + o);
            xq.x += al[0] * pq.x; xq.y += al[1] * pq.y;
            xq.z += al[2] * pq.z; xq.w += al[3] * pq.w;
        }
        if (iter == CG_IT - 1) {
            out[(size_t)(q * 4 + 0) * N + n] = xq.x;
            out[(size_t)(q * 4 + 1) * N + n] = xq.y;
            out[(size_t)(q * 4 + 2) * N + n] = xq.z;
            out[(size_t)(q * 4 + 3) * N + n] = xq.w;
        } else {
            *(float4*)(x + o) = xq;
            float4 sq = *(const float4*)(s + o);
            float4 rq = *(const float4*)(r + o);
            rq.x -= al[0] * sq.x; rq.y -= al[1] * sq.y;
            rq.z -= al[2] * sq.z; rq.w -= al[3] * sq.w;
            *(float4*)(r + o) = rq;
            part[0] = rq.x * rq.x; part[1] = rq.y * rq.y;
            part[2] = rq.z * rq.z; part[3] = rq.w * rq.w;
        }
    }
    if (iter != CG_IT - 1)  // uniform branch: whole grid takes same path
        reduce_q4_atomic(part, lds, sc + GAM + 16 * (iter + 1));
}

extern "C" void kernel_launch(void* const* d_in, const int* in_sizes, int n_in,
                              void* d_out, int out_size, void* d_ws, size_t ws_size,
                              hipStream_t stream) {
    const float* x   = (const float*)d_in[0];
    const int*   nl  = (const int*)d_in[1];
    const float* emb = (const float*)d_in[2];
    const float* fcw = (const float*)d_in[3];
    const float* fcb = (const float*)d_in[4];
    const float* th  = (const float*)d_in[5];
    int N = in_sizes[1] / KK;   // 50000

    float* sc  = (float*)d_ws;               // 512 scalar slots
    float* wl  = sc + 512;                   // N*16 laplacian weights
    float* big = wl + (size_t)N * 16;        // N*64 reused region
    float* ffp = big;                        // (N,16,4) features, dead after k_weights
    float* p   = big;                        // N*16   (born in k_apply iter 0)
    float* s   = big + (size_t)N * 16;       // N*16   (born in k_apply iter 0)
    float* xk  = big + (size_t)N * 32;       // N*16   (born in k_upd  iter 0)
    float* r   = big + (size_t)N * 48;       // N*16   (born in k_init, after weights)

    int G1 = (N + 255) / 256;
    int GW = (N * 16 + 255) / 256;
    int G4 = (N * 4 + 255) / 256;

    k_zero_scalars<<<1, 512, 0, stream>>>(sc);
    k_feat<<<G1, 256, 0, stream>>>(x, emb, fcw, fcb, ffp, N);
    k_weights<<<GW, 256, 0, stream>>>(nl, ffp, th, wl, sc, N);
    k_scale<<<1, 64, 0, stream>>>(sc);
    k_init<<<G4, 256, 0, stream>>>(x, r, sc, N);

    for (int i = 0; i < CG_IT; ++i) {
        k_apply<<<G4, 256, 0, stream>>>(wl, nl, r, p, s, sc, i, N);
        k_upd<<<G4, 256, 0, stream>>>(sc, xk, p, s, r, (float*)d_out, i, N);
    }
}